// Round 15
// baseline (154.701 us; speedup 1.0000x reference)
//
#include <hip/hip_runtime.h>
#include <math.h>

#define TT 512
#define NB 32
#define NRSTEP 200
#define KSC 14.4269504f          // 10 * log2(e); u = KSC * R
#define MAGICF 0x5CA1AB1E

// Schraudolph fast 2^a for a in [-5, 0] (verified R8/R10/R12)
#define SCHR_SCALE (-KSC * 8388608.0f)
#define SCHR_OFF   1064986823.0f         // 127*2^23 - 366393

typedef float float2v __attribute__((ext_vector_type(2)));

// DPP wave_shr:1 — lane i <- lane i-1, lane 0 gets 0 (verified R5..R12)
__device__ __forceinline__ float dpp_up1_f(float x) {
    return __int_as_float(__builtin_amdgcn_update_dpp(
        0, __float_as_int(x), 0x138, 0xf, 0xf, false));
}
__device__ __forceinline__ int dpp_up1_i(int x) {
    return __builtin_amdgcn_update_dpp(0, x, 0x138, 0xf, 0xf, false);
}
// DPP wave_shl:1 — lane i <- lane i+1, lane 63 gets 0 (HW-verified R13/R14:
// v_out output passed both rounds)
__device__ __forceinline__ float dpp_dn1_f(float x) {
    return __int_as_float(__builtin_amdgcn_update_dpp(
        0, __float_as_int(x), 0x130, 0xf, 0xf, false));
}
__device__ __forceinline__ float rdlane_f(float v, int lane) {
    return __int_as_float(__builtin_amdgcn_readlane(__float_as_int(v), lane));
}
__device__ __forceinline__ float exp2i(int e) {   // 2^e, |e|<=126, no trans op
    return __int_as_float((e + 127) << 23);
}
// magic-constant reciprocal + 1 Newton (~0.1% max err; verified R12)
__device__ __forceinline__ float fastrcp(float a) {
    float r = __int_as_float(0x7EF311C3 - __float_as_int(a));
    return r * (2.0f - a * r);
}

// ---------------- Fused kernel: gather + HUX + stats + soft-DTW + finalize ----
// one block (one wave) per batch b; lane owns rows t = lane*8 .. lane*8+7
// DP: R10/R12-proven w-domain 2-group packed sweep with exact per-substep
// exponent tracking. (Phase-peeled variant R13/R14 failed — retired.)
// ws: per-block slot of 8 floats at ws+8*b: {sab, ssq, corr, dtwv, flag, ...}
__global__ __launch_bounds__(64, 1) void fused_kernel(
    const float* __restrict__ pred_map,  // [B,1,T,128]
    const int*   __restrict__ lat_idx,   // [B,T]
    const float* __restrict__ omega,     // [B]
    const float* __restrict__ omni,      // [B,T]
    float*       __restrict__ out,       // v_out at [0, B*T), scalars after
    float*       __restrict__ ws)
{
    const int b    = blockIdx.x;
    const int lane = threadIdx.x;
    const int t0   = lane * 8;
    const bool lane0 = (lane == 0);

    // ---- gather v_in ----
    float v[8];
    const int*   li = lat_idx + b * TT + t0;
    const float* pm = pred_map + (size_t)b * TT * 128 + (size_t)t0 * 128;
    #pragma unroll
    for (int k = 0; k < 8; ++k) v[k] = pm[k * 128 + li[k]];

    // ---- HUX-f: 200 upwind steps; wrap-shuffle via DPP shl1 + readlane ----
    const float c = (float)(673089.75 / (2.0 * M_PI / 512.0)) * omega[b];
    #pragma unroll 1
    for (int it = 0; it < NRSTEP; ++it) {
        float rd0 = rdlane_f(v[0], 0);       // old v[0] of lane 0 (wrap source)
        float vn  = dpp_dn1_f(v[0]);         // old v[t0+8] (lane i <- i+1)
        vn = (lane == 63) ? rd0 : vn;        // wrap 512 -> 0
        #pragma unroll
        for (int k = 0; k < 7; ++k) {
            float r = fastrcp(fmaxf(v[k], 1.0f));
            v[k] = v[k] + c * r * (v[k + 1] - v[k]);
        }
        float r7 = fastrcp(fmaxf(v[7], 1.0f));
        v[7] = v[7] + c * r7 * (vn - v[7]);
    }

    // ---- write v_out ----
    float4* o4 = (float4*)(out + b * TT + t0);
    o4[0] = make_float4(v[0], v[1], v[2], v[3]);
    o4[1] = make_float4(v[4], v[5], v[6], v[7]);

    // ---- scaled series + per-b stats ----
    float x[8], y8[8];
    const float* om = omni + b * TT + t0;
    float sx = 0.f, syy0 = 0.f;
    #pragma unroll
    for (int k = 0; k < 8; ++k) {
        x[k]  = (om[k] - 200.0f) * 1e-3f;   // omni_scaled (rows)
        y8[k] = (v[k] - 200.0f) * 1e-3f;    // v_out_scaled (cols)
        sx += x[k];
        syy0 += y8[k];
    }
    #pragma unroll
    for (int m = 1; m < 64; m <<= 1) {
        sx   += __shfl_xor(sx, m, 64);
        syy0 += __shfl_xor(syy0, m, 64);
    }
    const float mx = sx * (1.0f / 512.0f);
    const float my = syy0 * (1.0f / 512.0f);

    float sab = 0.f, ssq = 0.f, snum = 0.f, sxx = 0.f, spp = 0.f;
    #pragma unroll
    for (int k = 0; k < 8; ++k) {
        float d = y8[k] - x[k];
        sab += fabsf(d);
        ssq += d * d;
        float pc = y8[k] - my;
        float tc = x[k] - mx;
        snum += pc * tc;
        sxx  += tc * tc;
        spp  += pc * pc;
    }
    #pragma unroll
    for (int m = 1; m < 64; m <<= 1) {
        sab  += __shfl_xor(sab,  m, 64);
        ssq  += __shfl_xor(ssq,  m, 64);
        snum += __shfl_xor(snum, m, 64);
        sxx  += __shfl_xor(sxx,  m, 64);
        spp  += __shfl_xor(spp,  m, 64);
    }
    const float corr = snum / (sqrtf(spp) * sqrtf(sxx));

    // ---- soft-DTW, w-domain, 2-group packed, exact per-substep scales ----
    float2v x2[4];
    #pragma unroll
    for (int i = 0; i < 4; ++i) { x2[i].x = x[i]; x2[i].y = x[i + 4]; }

    float2v P[4];
    #pragma unroll
    for (int k = 0; k < 4; ++k) P[k] = (float2v){0.0f, 0.0f};
    int   E = 0;
    float c7w = 0.0f; int c7E = 0;    // published boundary (B-tail, row 8l+7)
    float aT = 0.0f, aT2 = 0.0f;      // A-tail (row 8l+3) delay line -> B-chain
    float pW = 0.0f;  int pE = 0;     // lane l-1 B-tail, two substeps back
    int   vj0 = -2 * lane;            // A-group col for upcoming substep
    const float adoptW = lane0 ? 1.0f : 0.0f;  // diag at adopt: origin / BIG

    // y pipeline: before substep s, zA(l) = y[s-2l], zB(l) = y[s-1-2l]
    float zA = lane0 ? y8[0] : 0.0f;
    float zB = 0.0f;

    #pragma unroll 1
    for (int blk = 0; blk < 80; ++blk) {
        const int us  = blk < 63 ? blk : 63;
        const int us1 = blk < 62 ? blk + 1 : 63;   // readlane idx must be <= 63
        float f[8];
        f[0] = rdlane_f(y8[1], us);
        f[1] = rdlane_f(y8[2], us);
        f[2] = rdlane_f(y8[3], us);
        f[3] = rdlane_f(y8[4], us);
        f[4] = rdlane_f(y8[5], us);
        f[5] = rdlane_f(y8[6], us);
        f[6] = rdlane_f(y8[7], us);
        f[7] = rdlane_f(y8[0], us1);

        #pragma unroll
        for (int q = 0; q < 8; ++q) {
            float nW  = dpp_up1_f(c7w);   // lane l-1 B-tail at col j0 (scale nEc)
            int   nEc = dpp_up1_i(c7E);

            // D-factors (Schraudolph), packed {row k @ zA, row k+4 @ zB}
            float2v z2; z2.x = zA; z2.y = zB;
            float2v fsv[4];
            #pragma unroll
            for (int i = 0; i < 4; ++i) {
                float2v t = x2[i] - z2;
                float2v h = (t * t) * (float2v){SCHR_SCALE, SCHR_SCALE}
                          + (float2v){SCHR_OFF, SCHR_OFF};
                fsv[i].x = __int_as_float((int)h.x);
                fsv[i].y = __int_as_float((int)h.y);
            }

            const bool adopt = (vj0 == 0);
            E = adopt ? nEc : E;          // adopt neighbor scale exactly
            float wuA = ldexpf(nW, E - nEc);   // up for A-head, our scale
            float wdA = ldexpf(pW, E - pE);    // diag for A-head
            wdA = adopt ? adoptW : wdA;        // col -1 = BIG; lane0 origin

            float2v uc, dgn;
            uc.x  = wuA; uc.y  = aT;      // B-head up = own A-tail (s-1)
            dgn.x = wdA; dgn.y = aT2;     // B-head diag = own A-tail (s-2)
            #pragma unroll
            for (int k = 0; k < 4; ++k) {
                float2v wl = P[k];
                float2v a  = fsv[k] * (wl + dgn);   // left+diag, off the chain
                float2v w  = fsv[k] * uc + a;       // packed fma chain
                dgn = wl; P[k] = w; uc = w;
            }
            aT2 = aT; aT = P[3].x;

            const bool pub = ((unsigned)(vj0 - 1) < 512u);  // B col valid
            c7w = pub ? P[3].y : c7w;
            c7E = pub ? E : c7E;
            pW = nW; pE = nEc;

            float zn = dpp_up1_f(zB);     // 2-substep/lane y delay line
            zB = zA;
            zA = lane0 ? f[q] : zn;
            ++vj0;
        }

        // per-blk renorm: B-tail -> ~[1,2); rescale (P,E) and the published
        // (c7w,c7E) together — implied u invariant, so snapshots stay exact.
        int ebits = (int)((__float_as_uint(P[3].y) >> 23) & 255u);
        int dsh = 127 - ebits;
        dsh = dsh > 126 ? 126 : (dsh < -126 ? -126 : dsh);
        float sf = exp2i(dsh);
        E += dsh;
        float2v sf2; sf2.x = sf; sf2.y = sf;
        #pragma unroll
        for (int k = 0; k < 4; ++k) P[k] = P[k] * sf2;
        aT *= sf; aT2 *= sf;
        c7w *= sf; c7E += dsh;
    }

    float dtwv = 0.0f;
    if (lane == 63) {
        float u = (float)c7E - __builtin_amdgcn_logf(c7w);  // v_log = log2
        dtwv = fabsf(u) * (1.0f / KSC);                     // |R(511,511)|
    }

    // ---- init-free cross-block finalize (flag protocol; verified R12) ----
    float* slot = ws + 8 * b;
    if (lane == 63) slot[3] = dtwv;
    if (lane == 0) { slot[0] = sab; slot[1] = ssq; slot[2] = corr; }
    __syncthreads();
    __threadfence();
    if (lane == 0) atomicExch((int*)(slot + 4), MAGICF);   // release-publish

    if (b == NB - 1) {
        float m = 0.f, s = 0.f, p = 0.f, d = 0.f;
        if (lane < NB) {
            int* fl = (int*)(ws + 8 * lane + 4);
            while (atomicAdd(fl, 0) != MAGICF) { }         // acquire-spin
            __threadfence();
            float* sl = ws + 8 * lane;
            m = atomicAdd(&sl[0], 0.0f);
            s = atomicAdd(&sl[1], 0.0f);
            p = atomicAdd(&sl[2], 0.0f);
            d = atomicAdd(&sl[3], 0.0f);
        }
        #pragma unroll
        for (int mm = 1; mm < 64; mm <<= 1) {
            m += __shfl_xor(m, mm, 64);
            s += __shfl_xor(s, mm, 64);
            p += __shfl_xor(p, mm, 64);
            d += __shfl_xor(d, mm, 64);
        }
        if (lane == 0) {
            out[NB * TT + 0] = m;                         // mae_loss
            out[NB * TT + 1] = 1.0f - p * (1.0f / 32.0f); // pcc_loss
            out[NB * TT + 2] = d * (1.0f / 32.0f);        // dtw_loss
            out[NB * TT + 3] = sqrtf(s);                  // rmse_loss
        }
    }
}

extern "C" void kernel_launch(void* const* d_in, const int* in_sizes, int n_in,
                              void* d_out, int out_size, void* d_ws, size_t ws_size,
                              hipStream_t stream) {
    const float* pred_map = (const float*)d_in[0];
    const int*   lat_idx  = (const int*)d_in[1];
    const float* omega    = (const float*)d_in[2];
    const float* omni     = (const float*)d_in[3];
    float* out = (float*)d_out;
    float* ws  = (float*)d_ws;

    fused_kernel<<<NB, 64, 0, stream>>>(pred_map, lat_idx, omega, omni, out, ws);
}

// Round 17
// 151.256 us; speedup vs baseline: 1.0228x; 1.0228x over previous
//
#include <hip/hip_runtime.h>
#include <math.h>

#define TT 512
#define NB 32
#define NRSTEP 200
#define KSC 14.4269504f          // 10 * log2(e); u = KSC * R
#define MAGICF 0x5CA1AB1E

// Schraudolph fast 2^a for a in [-5, 0] (verified R8/R10/R12/R15)
#define SCHR_SCALE (-KSC * 8388608.0f)
#define SCHR_OFF   1064986823.0f         // 127*2^23 - 366393

typedef float float2v __attribute__((ext_vector_type(2)));

// DPP wave_shr:1 — lane i <- lane i-1, lane 0 gets 0 (verified R5..R15)
__device__ __forceinline__ float dpp_up1_f(float x) {
    return __int_as_float(__builtin_amdgcn_update_dpp(
        0, __float_as_int(x), 0x138, 0xf, 0xf, false));
}
__device__ __forceinline__ int dpp_up1_i(int x) {
    return __builtin_amdgcn_update_dpp(0, x, 0x138, 0xf, 0xf, false);
}
// DPP wave_shl:1 — lane i <- lane i+1, lane 63 gets 0 (HW-verified R13..R15)
__device__ __forceinline__ float dpp_dn1_f(float x) {
    return __int_as_float(__builtin_amdgcn_update_dpp(
        0, __float_as_int(x), 0x130, 0xf, 0xf, false));
}
__device__ __forceinline__ float rdlane_f(float v, int lane) {
    return __int_as_float(__builtin_amdgcn_readlane(__float_as_int(v), lane));
}
__device__ __forceinline__ float exp2i(int e) {   // 2^e, |e|<=126, no trans op
    return __int_as_float((e + 127) << 23);
}
// magic-constant reciprocal + 1 Newton, componentwise (verified R12/R15)
__device__ __forceinline__ float2v fastrcp2(float2v a) {
    float2v r;
    r.x = __int_as_float(0x7EF311C3 - __float_as_int(a.x));
    r.y = __int_as_float(0x7EF311C3 - __float_as_int(a.y));
    return r * ((float2v){2.0f, 2.0f} - a * r);
}
__device__ __forceinline__ float2v max1_2(float2v a) {
    float2v m; m.x = fmaxf(a.x, 1.0f); m.y = fmaxf(a.y, 1.0f); return m;
}

// ---------------- Fused kernel: gather + HUX + stats + soft-DTW + finalize ----
// one block (one wave) per batch b; lane owns rows t = lane*8 .. lane*8+7
// DP: R15-proven MONOLITHIC w-domain 2-group packed sweep with exact
// per-substep exponent tracking. (Loop-split variants R13/R14/R16 all failed
// with source-invisible cause — do NOT split this loop.)
// HUX: row updates all read old values -> packed float2v (this round's change).
__global__ __launch_bounds__(64, 1) void fused_kernel(
    const float* __restrict__ pred_map,  // [B,1,T,128]
    const int*   __restrict__ lat_idx,   // [B,T]
    const float* __restrict__ omega,     // [B]
    const float* __restrict__ omni,      // [B,T]
    float*       __restrict__ out,       // v_out at [0, B*T), scalars after
    float*       __restrict__ ws)
{
    const int b    = blockIdx.x;
    const int lane = threadIdx.x;
    const int t0   = lane * 8;
    const bool lane0 = (lane == 0);

    // ---- gather v_in ----
    float v[8];
    const int*   li = lat_idx + b * TT + t0;
    const float* pm = pred_map + (size_t)b * TT * 128 + (size_t)t0 * 128;
    #pragma unroll
    for (int k = 0; k < 8; ++k) v[k] = pm[k * 128 + li[k]];

    // ---- HUX-f: 200 upwind steps, packed: W[i] = {v[i], v[i+4]} ----
    // neighbors: nb[i] = {v[i+1], v[i+5]} = W[i+1] for i<3; nb[3] = {v[4], vn}
    const float c = (float)(673089.75 / (2.0 * M_PI / 512.0)) * omega[b];
    const float2v c2 = {c, c};
    float2v W[4];
    W[0].x = v[0]; W[0].y = v[4];
    W[1].x = v[1]; W[1].y = v[5];
    W[2].x = v[2]; W[2].y = v[6];
    W[3].x = v[3]; W[3].y = v[7];
    #pragma unroll 1
    for (int it = 0; it < NRSTEP; ++it) {
        float rd0 = rdlane_f(W[0].x, 0);     // old v[0] of lane 0 (wrap source)
        float vn  = dpp_dn1_f(W[0].x);       // old v[t0+8] (lane i <- i+1)
        vn = (lane == 63) ? rd0 : vn;        // wrap 512 -> 0
        // old-value neighbor copies BEFORE any update
        float2v nb0 = W[1], nb1 = W[2], nb2 = W[3];
        float2v nb3; nb3.x = W[0].y; nb3.y = vn;
        float2v r0 = fastrcp2(max1_2(W[0]));
        float2v r1 = fastrcp2(max1_2(W[1]));
        float2v r2 = fastrcp2(max1_2(W[2]));
        float2v r3 = fastrcp2(max1_2(W[3]));
        W[0] = W[0] + c2 * r0 * (nb0 - W[0]);
        W[1] = W[1] + c2 * r1 * (nb1 - W[1]);
        W[2] = W[2] + c2 * r2 * (nb2 - W[2]);
        W[3] = W[3] + c2 * r3 * (nb3 - W[3]);
    }
    v[0] = W[0].x; v[4] = W[0].y;
    v[1] = W[1].x; v[5] = W[1].y;
    v[2] = W[2].x; v[6] = W[2].y;
    v[3] = W[3].x; v[7] = W[3].y;

    // ---- write v_out ----
    float4* o4 = (float4*)(out + b * TT + t0);
    o4[0] = make_float4(v[0], v[1], v[2], v[3]);
    o4[1] = make_float4(v[4], v[5], v[6], v[7]);

    // ---- scaled series + per-b stats ----
    float x[8], y8[8];
    const float* om = omni + b * TT + t0;
    float sx = 0.f, syy0 = 0.f;
    #pragma unroll
    for (int k = 0; k < 8; ++k) {
        x[k]  = (om[k] - 200.0f) * 1e-3f;   // omni_scaled (rows)
        y8[k] = (v[k] - 200.0f) * 1e-3f;    // v_out_scaled (cols)
        sx += x[k];
        syy0 += y8[k];
    }
    #pragma unroll
    for (int m = 1; m < 64; m <<= 1) {
        sx   += __shfl_xor(sx, m, 64);
        syy0 += __shfl_xor(syy0, m, 64);
    }
    const float mx = sx * (1.0f / 512.0f);
    const float my = syy0 * (1.0f / 512.0f);

    float sab = 0.f, ssq = 0.f, snum = 0.f, sxx = 0.f, spp = 0.f;
    #pragma unroll
    for (int k = 0; k < 8; ++k) {
        float d = y8[k] - x[k];
        sab += fabsf(d);
        ssq += d * d;
        float pc = y8[k] - my;
        float tc = x[k] - mx;
        snum += pc * tc;
        sxx  += tc * tc;
        spp  += pc * pc;
    }
    #pragma unroll
    for (int m = 1; m < 64; m <<= 1) {
        sab  += __shfl_xor(sab,  m, 64);
        ssq  += __shfl_xor(ssq,  m, 64);
        snum += __shfl_xor(snum, m, 64);
        sxx  += __shfl_xor(sxx,  m, 64);
        spp  += __shfl_xor(spp,  m, 64);
    }
    const float corr = snum / (sqrtf(spp) * sqrtf(sxx));

    // ---- soft-DTW, w-domain, 2-group packed, exact per-substep scales ----
    // (monolithic 80-blk loop — R15-proven, unchanged)
    float2v x2[4];
    #pragma unroll
    for (int i = 0; i < 4; ++i) { x2[i].x = x[i]; x2[i].y = x[i + 4]; }

    float2v P[4];
    #pragma unroll
    for (int k = 0; k < 4; ++k) P[k] = (float2v){0.0f, 0.0f};
    int   E = 0;
    float c7w = 0.0f; int c7E = 0;    // published boundary (B-tail, row 8l+7)
    float aT = 0.0f, aT2 = 0.0f;      // A-tail (row 8l+3) delay line -> B-chain
    float pW = 0.0f;  int pE = 0;     // lane l-1 B-tail, two substeps back
    int   vj0 = -2 * lane;            // A-group col for upcoming substep
    const float adoptW = lane0 ? 1.0f : 0.0f;  // diag at adopt: origin / BIG

    // y pipeline: before substep s, zA(l) = y[s-2l], zB(l) = y[s-1-2l]
    float zA = lane0 ? y8[0] : 0.0f;
    float zB = 0.0f;

    #pragma unroll 1
    for (int blk = 0; blk < 80; ++blk) {
        const int us  = blk < 63 ? blk : 63;
        const int us1 = blk < 62 ? blk + 1 : 63;   // readlane idx must be <= 63
        float f[8];
        f[0] = rdlane_f(y8[1], us);
        f[1] = rdlane_f(y8[2], us);
        f[2] = rdlane_f(y8[3], us);
        f[3] = rdlane_f(y8[4], us);
        f[4] = rdlane_f(y8[5], us);
        f[5] = rdlane_f(y8[6], us);
        f[6] = rdlane_f(y8[7], us);
        f[7] = rdlane_f(y8[0], us1);

        #pragma unroll
        for (int q = 0; q < 8; ++q) {
            float nW  = dpp_up1_f(c7w);   // lane l-1 B-tail at col j0 (scale nEc)
            int   nEc = dpp_up1_i(c7E);

            // D-factors (Schraudolph), packed {row k @ zA, row k+4 @ zB}
            float2v z2; z2.x = zA; z2.y = zB;
            float2v fsv[4];
            #pragma unroll
            for (int i = 0; i < 4; ++i) {
                float2v t = x2[i] - z2;
                float2v h = (t * t) * (float2v){SCHR_SCALE, SCHR_SCALE}
                          + (float2v){SCHR_OFF, SCHR_OFF};
                fsv[i].x = __int_as_float((int)h.x);
                fsv[i].y = __int_as_float((int)h.y);
            }

            const bool adopt = (vj0 == 0);
            E = adopt ? nEc : E;          // adopt neighbor scale exactly
            float wuA = ldexpf(nW, E - nEc);   // up for A-head, our scale
            float wdA = ldexpf(pW, E - pE);    // diag for A-head
            wdA = adopt ? adoptW : wdA;        // col -1 = BIG; lane0 origin

            float2v uc, dgn;
            uc.x  = wuA; uc.y  = aT;      // B-head up = own A-tail (s-1)
            dgn.x = wdA; dgn.y = aT2;     // B-head diag = own A-tail (s-2)
            #pragma unroll
            for (int k = 0; k < 4; ++k) {
                float2v wl = P[k];
                float2v a  = fsv[k] * (wl + dgn);   // left+diag, off the chain
                float2v w  = fsv[k] * uc + a;       // packed fma chain
                dgn = wl; P[k] = w; uc = w;
            }
            aT2 = aT; aT = P[3].x;

            const bool pub = ((unsigned)(vj0 - 1) < 512u);  // B col valid
            c7w = pub ? P[3].y : c7w;
            c7E = pub ? E : c7E;
            pW = nW; pE = nEc;

            float zn = dpp_up1_f(zB);     // 2-substep/lane y delay line
            zB = zA;
            zA = lane0 ? f[q] : zn;
            ++vj0;
        }

        // per-blk renorm: B-tail -> ~[1,2); rescale (P,E) and the published
        // (c7w,c7E) together — implied u invariant, so snapshots stay exact.
        int ebits = (int)((__float_as_uint(P[3].y) >> 23) & 255u);
        int dsh = 127 - ebits;
        dsh = dsh > 126 ? 126 : (dsh < -126 ? -126 : dsh);
        float sf = exp2i(dsh);
        E += dsh;
        float2v sf2; sf2.x = sf; sf2.y = sf;
        #pragma unroll
        for (int k = 0; k < 4; ++k) P[k] = P[k] * sf2;
        aT *= sf; aT2 *= sf;
        c7w *= sf; c7E += dsh;
    }

    float dtwv = 0.0f;
    if (lane == 63) {
        float u = (float)c7E - __builtin_amdgcn_logf(c7w);  // v_log = log2
        dtwv = fabsf(u) * (1.0f / KSC);                     // |R(511,511)|
    }

    // ---- init-free cross-block finalize (flag protocol; verified R12/R15) ----
    float* slot = ws + 8 * b;
    if (lane == 63) slot[3] = dtwv;
    if (lane == 0) { slot[0] = sab; slot[1] = ssq; slot[2] = corr; }
    __syncthreads();
    __threadfence();
    if (lane == 0) atomicExch((int*)(slot + 4), MAGICF);   // release-publish

    if (b == NB - 1) {
        float m = 0.f, s = 0.f, p = 0.f, d = 0.f;
        if (lane < NB) {
            int* fl = (int*)(ws + 8 * lane + 4);
            while (atomicAdd(fl, 0) != MAGICF) { }         // acquire-spin
            __threadfence();
            float* sl = ws + 8 * lane;
            m = atomicAdd(&sl[0], 0.0f);
            s = atomicAdd(&sl[1], 0.0f);
            p = atomicAdd(&sl[2], 0.0f);
            d = atomicAdd(&sl[3], 0.0f);
        }
        #pragma unroll
        for (int mm = 1; mm < 64; mm <<= 1) {
            m += __shfl_xor(m, mm, 64);
            s += __shfl_xor(s, mm, 64);
            p += __shfl_xor(p, mm, 64);
            d += __shfl_xor(d, mm, 64);
        }
        if (lane == 0) {
            out[NB * TT + 0] = m;                         // mae_loss
            out[NB * TT + 1] = 1.0f - p * (1.0f / 32.0f); // pcc_loss
            out[NB * TT + 2] = d * (1.0f / 32.0f);        // dtw_loss
            out[NB * TT + 3] = sqrtf(s);                  // rmse_loss
        }
    }
}

extern "C" void kernel_launch(void* const* d_in, const int* in_sizes, int n_in,
                              void* d_out, int out_size, void* d_ws, size_t ws_size,
                              hipStream_t stream) {
    const float* pred_map = (const float*)d_in[0];
    const int*   lat_idx  = (const int*)d_in[1];
    const float* omega    = (const float*)d_in[2];
    const float* omni     = (const float*)d_in[3];
    float* out = (float*)d_out;
    float* ws  = (float*)d_ws;

    fused_kernel<<<NB, 64, 0, stream>>>(pred_map, lat_idx, omega, omni, out, ws);
}

// Round 18
// 148.932 us; speedup vs baseline: 1.0387x; 1.0156x over previous
//
#include <hip/hip_runtime.h>
#include <math.h>

#define TT 512
#define NB 32
#define NRSTEP 200
#define KSC 14.4269504f          // 10 * log2(e); u = KSC * R
#define MAGICF 0x5CA1AB1E

// Schraudolph fast 2^a for a in [-5, 0] (verified R8/R10/R12/R15/R17)
#define SCHR_SCALE (-KSC * 8388608.0f)
#define SCHR_OFF   1064986823.0f         // 127*2^23 - 366393

typedef float float2v __attribute__((ext_vector_type(2)));

// ---- forced VOP3P packed f32 ops (dual-issue FP32, gfx90a+/gfx950) ----
__device__ __forceinline__ float2v pk_add(float2v a, float2v b) {
    float2v d;
    asm("v_pk_add_f32 %0, %1, %2" : "=v"(d) : "v"(a), "v"(b));
    return d;
}
__device__ __forceinline__ float2v pk_mul(float2v a, float2v b) {
    float2v d;
    asm("v_pk_mul_f32 %0, %1, %2" : "=v"(d) : "v"(a), "v"(b));
    return d;
}
__device__ __forceinline__ float2v pk_fma(float2v a, float2v b, float2v c) {
    float2v d;
    asm("v_pk_fma_f32 %0, %1, %2, %3" : "=v"(d) : "v"(a), "v"(b), "v"(c));
    return d;
}

// DPP wave_shr:1 — lane i <- lane i-1, lane 0 gets 0 (verified R5..R17)
__device__ __forceinline__ float dpp_up1_f(float x) {
    return __int_as_float(__builtin_amdgcn_update_dpp(
        0, __float_as_int(x), 0x138, 0xf, 0xf, false));
}
__device__ __forceinline__ int dpp_up1_i(int x) {
    return __builtin_amdgcn_update_dpp(0, x, 0x138, 0xf, 0xf, false);
}
// DPP wave_shl:1 — lane i <- lane i+1, lane 63 gets 0 (HW-verified R13..R17)
__device__ __forceinline__ float dpp_dn1_f(float x) {
    return __int_as_float(__builtin_amdgcn_update_dpp(
        0, __float_as_int(x), 0x130, 0xf, 0xf, false));
}
__device__ __forceinline__ float rdlane_f(float v, int lane) {
    return __int_as_float(__builtin_amdgcn_readlane(__float_as_int(v), lane));
}
__device__ __forceinline__ float exp2i(int e) {   // 2^e, |e|<=126, no trans op
    return __int_as_float((e + 127) << 23);
}
// magic-constant reciprocal + 1 Newton, componentwise (verified R12/R15/R17)
__device__ __forceinline__ float2v fastrcp2(float2v a) {
    float2v r;
    r.x = __int_as_float(0x7EF311C3 - __float_as_int(a.x));
    r.y = __int_as_float(0x7EF311C3 - __float_as_int(a.y));
    return r * ((float2v){2.0f, 2.0f} - a * r);
}
__device__ __forceinline__ float2v max1_2(float2v a) {
    float2v m; m.x = fmaxf(a.x, 1.0f); m.y = fmaxf(a.y, 1.0f); return m;
}

// ---------------- Fused kernel: gather + HUX + stats + soft-DTW + finalize ----
// one block (one wave) per batch b; lane owns rows t = lane*8 .. lane*8+7
// DP: R15/R17-proven MONOLITHIC w-domain 2-group packed sweep, exact
// per-substep exponent tracking. (Loop-split variants R13/R14/R16 all failed
// with source-invisible cause — do NOT split this loop.)
// R18: hot packed math forced to v_pk_* via inline asm; y-pipeline carries
// NEGATED y so the D-term is pk_add(x2, z2n) with no modifiers (bit-identical).
__global__ __launch_bounds__(64, 1) void fused_kernel(
    const float* __restrict__ pred_map,  // [B,1,T,128]
    const int*   __restrict__ lat_idx,   // [B,T]
    const float* __restrict__ omega,     // [B]
    const float* __restrict__ omni,      // [B,T]
    float*       __restrict__ out,       // v_out at [0, B*T), scalars after
    float*       __restrict__ ws)
{
    const int b    = blockIdx.x;
    const int lane = threadIdx.x;
    const int t0   = lane * 8;
    const bool lane0 = (lane == 0);

    // ---- gather v_in ----
    float v[8];
    const int*   li = lat_idx + b * TT + t0;
    const float* pm = pred_map + (size_t)b * TT * 128 + (size_t)t0 * 128;
    #pragma unroll
    for (int k = 0; k < 8; ++k) v[k] = pm[k * 128 + li[k]];

    // ---- HUX-f: 200 upwind steps, packed: W[i] = {v[i], v[i+4]} (R17) ----
    const float c = (float)(673089.75 / (2.0 * M_PI / 512.0)) * omega[b];
    const float2v c2 = {c, c};
    float2v W[4];
    W[0].x = v[0]; W[0].y = v[4];
    W[1].x = v[1]; W[1].y = v[5];
    W[2].x = v[2]; W[2].y = v[6];
    W[3].x = v[3]; W[3].y = v[7];
    #pragma unroll 1
    for (int it = 0; it < NRSTEP; ++it) {
        float rd0 = rdlane_f(W[0].x, 0);     // old v[0] of lane 0 (wrap source)
        float vn  = dpp_dn1_f(W[0].x);       // old v[t0+8] (lane i <- i+1)
        vn = (lane == 63) ? rd0 : vn;        // wrap 512 -> 0
        float2v nb0 = W[1], nb1 = W[2], nb2 = W[3];
        float2v nb3; nb3.x = W[0].y; nb3.y = vn;
        float2v r0 = fastrcp2(max1_2(W[0]));
        float2v r1 = fastrcp2(max1_2(W[1]));
        float2v r2 = fastrcp2(max1_2(W[2]));
        float2v r3 = fastrcp2(max1_2(W[3]));
        W[0] = W[0] + c2 * r0 * (nb0 - W[0]);
        W[1] = W[1] + c2 * r1 * (nb1 - W[1]);
        W[2] = W[2] + c2 * r2 * (nb2 - W[2]);
        W[3] = W[3] + c2 * r3 * (nb3 - W[3]);
    }
    v[0] = W[0].x; v[4] = W[0].y;
    v[1] = W[1].x; v[5] = W[1].y;
    v[2] = W[2].x; v[6] = W[2].y;
    v[3] = W[3].x; v[7] = W[3].y;

    // ---- write v_out ----
    float4* o4 = (float4*)(out + b * TT + t0);
    o4[0] = make_float4(v[0], v[1], v[2], v[3]);
    o4[1] = make_float4(v[4], v[5], v[6], v[7]);

    // ---- scaled series + per-b stats ----
    float x[8], y8[8], y8n[8];
    const float* om = omni + b * TT + t0;
    float sx = 0.f, syy0 = 0.f;
    #pragma unroll
    for (int k = 0; k < 8; ++k) {
        x[k]   = (om[k] - 200.0f) * 1e-3f;   // omni_scaled (rows)
        y8[k]  = (v[k] - 200.0f) * 1e-3f;    // v_out_scaled (cols)
        y8n[k] = -y8[k];                     // negated for the DP y-pipeline
        sx += x[k];
        syy0 += y8[k];
    }
    #pragma unroll
    for (int m = 1; m < 64; m <<= 1) {
        sx   += __shfl_xor(sx, m, 64);
        syy0 += __shfl_xor(syy0, m, 64);
    }
    const float mx = sx * (1.0f / 512.0f);
    const float my = syy0 * (1.0f / 512.0f);

    float sab = 0.f, ssq = 0.f, snum = 0.f, sxx = 0.f, spp = 0.f;
    #pragma unroll
    for (int k = 0; k < 8; ++k) {
        float d = y8[k] - x[k];
        sab += fabsf(d);
        ssq += d * d;
        float pc = y8[k] - my;
        float tc = x[k] - mx;
        snum += pc * tc;
        sxx  += tc * tc;
        spp  += pc * pc;
    }
    #pragma unroll
    for (int m = 1; m < 64; m <<= 1) {
        sab  += __shfl_xor(sab,  m, 64);
        ssq  += __shfl_xor(ssq,  m, 64);
        snum += __shfl_xor(snum, m, 64);
        sxx  += __shfl_xor(sxx,  m, 64);
        spp  += __shfl_xor(spp,  m, 64);
    }
    const float corr = snum / (sqrtf(spp) * sqrtf(sxx));

    // ---- soft-DTW, w-domain, 2-group packed, exact per-substep scales ----
    // (monolithic 80-blk loop — proven; z pipeline carries NEGATED y)
    float2v x2[4];
    #pragma unroll
    for (int i = 0; i < 4; ++i) { x2[i].x = x[i]; x2[i].y = x[i + 4]; }
    const float2v kS2 = {SCHR_SCALE, SCHR_SCALE};
    const float2v kO2 = {SCHR_OFF, SCHR_OFF};

    float2v P[4];
    #pragma unroll
    for (int k = 0; k < 4; ++k) P[k] = (float2v){0.0f, 0.0f};
    int   E = 0;
    float c7w = 0.0f; int c7E = 0;    // published boundary (B-tail, row 8l+7)
    float aT = 0.0f, aT2 = 0.0f;      // A-tail (row 8l+3) delay line -> B-chain
    float pW = 0.0f;  int pE = 0;     // lane l-1 B-tail, two substeps back
    int   vj0 = -2 * lane;            // A-group col for upcoming substep
    const float adoptW = lane0 ? 1.0f : 0.0f;  // diag at adopt: origin / BIG

    // y pipeline (NEGATED): before substep s, zA(l) = -y[s-2l], zB(l) = -y[s-1-2l]
    float zA = lane0 ? y8n[0] : 0.0f;
    float zB = 0.0f;

    #pragma unroll 1
    for (int blk = 0; blk < 80; ++blk) {
        const int us  = blk < 63 ? blk : 63;
        const int us1 = blk < 62 ? blk + 1 : 63;   // readlane idx must be <= 63
        float f[8];
        f[0] = rdlane_f(y8n[1], us);
        f[1] = rdlane_f(y8n[2], us);
        f[2] = rdlane_f(y8n[3], us);
        f[3] = rdlane_f(y8n[4], us);
        f[4] = rdlane_f(y8n[5], us);
        f[5] = rdlane_f(y8n[6], us);
        f[6] = rdlane_f(y8n[7], us);
        f[7] = rdlane_f(y8n[0], us1);

        #pragma unroll
        for (int q = 0; q < 8; ++q) {
            float nW  = dpp_up1_f(c7w);   // lane l-1 B-tail at col j0 (scale nEc)
            int   nEc = dpp_up1_i(c7E);

            // D-factors (Schraudolph), forced v_pk_*: t = x + (-y) = pk_add
            float2v z2; z2.x = zA; z2.y = zB;
            float2v fsv[4];
            #pragma unroll
            for (int i = 0; i < 4; ++i) {
                float2v t  = pk_add(x2[i], z2);
                float2v t2 = pk_mul(t, t);
                float2v h  = pk_fma(t2, kS2, kO2);
                fsv[i].x = __int_as_float((int)h.x);
                fsv[i].y = __int_as_float((int)h.y);
            }

            const bool adopt = (vj0 == 0);
            E = adopt ? nEc : E;          // adopt neighbor scale exactly
            float wuA = ldexpf(nW, E - nEc);   // up for A-head, our scale
            float wdA = ldexpf(pW, E - pE);    // diag for A-head
            wdA = adopt ? adoptW : wdA;        // col -1 = BIG; lane0 origin

            float2v uc, dgn;
            uc.x  = wuA; uc.y  = aT;      // B-head up = own A-tail (s-1)
            dgn.x = wdA; dgn.y = aT2;     // B-head diag = own A-tail (s-2)
            #pragma unroll
            for (int k = 0; k < 4; ++k) {
                float2v wl = P[k];
                float2v s  = pk_add(wl, dgn);       // left+diag, off the chain
                float2v a  = pk_mul(fsv[k], s);
                float2v w  = pk_fma(fsv[k], uc, a); // packed fma chain
                dgn = wl; P[k] = w; uc = w;
            }
            aT2 = aT; aT = P[3].x;

            const bool pub = ((unsigned)(vj0 - 1) < 512u);  // B col valid
            c7w = pub ? P[3].y : c7w;
            c7E = pub ? E : c7E;
            pW = nW; pE = nEc;

            float zn = dpp_up1_f(zB);     // 2-substep/lane y delay line
            zB = zA;
            zA = lane0 ? f[q] : zn;
            ++vj0;
        }

        // per-blk renorm: B-tail -> ~[1,2); rescale (P,E) and the published
        // (c7w,c7E) together — implied u invariant, so snapshots stay exact.
        int ebits = (int)((__float_as_uint(P[3].y) >> 23) & 255u);
        int dsh = 127 - ebits;
        dsh = dsh > 126 ? 126 : (dsh < -126 ? -126 : dsh);
        float sf = exp2i(dsh);
        E += dsh;
        float2v sf2; sf2.x = sf; sf2.y = sf;
        #pragma unroll
        for (int k = 0; k < 4; ++k) P[k] = pk_mul(P[k], sf2);
        aT *= sf; aT2 *= sf;
        c7w *= sf; c7E += dsh;
    }

    float dtwv = 0.0f;
    if (lane == 63) {
        float u = (float)c7E - __builtin_amdgcn_logf(c7w);  // v_log = log2
        dtwv = fabsf(u) * (1.0f / KSC);                     // |R(511,511)|
    }

    // ---- init-free cross-block finalize (flag protocol; verified R12/R15/R17) ----
    float* slot = ws + 8 * b;
    if (lane == 63) slot[3] = dtwv;
    if (lane == 0) { slot[0] = sab; slot[1] = ssq; slot[2] = corr; }
    __syncthreads();
    __threadfence();
    if (lane == 0) atomicExch((int*)(slot + 4), MAGICF);   // release-publish

    if (b == NB - 1) {
        float m = 0.f, s = 0.f, p = 0.f, d = 0.f;
        if (lane < NB) {
            int* fl = (int*)(ws + 8 * lane + 4);
            while (atomicAdd(fl, 0) != MAGICF) { }         // acquire-spin
            __threadfence();
            float* sl = ws + 8 * lane;
            m = atomicAdd(&sl[0], 0.0f);
            s = atomicAdd(&sl[1], 0.0f);
            p = atomicAdd(&sl[2], 0.0f);
            d = atomicAdd(&sl[3], 0.0f);
        }
        #pragma unroll
        for (int mm = 1; mm < 64; mm <<= 1) {
            m += __shfl_xor(m, mm, 64);
            s += __shfl_xor(s, mm, 64);
            p += __shfl_xor(p, mm, 64);
            d += __shfl_xor(d, mm, 64);
        }
        if (lane == 0) {
            out[NB * TT + 0] = m;                         // mae_loss
            out[NB * TT + 1] = 1.0f - p * (1.0f / 32.0f); // pcc_loss
            out[NB * TT + 2] = d * (1.0f / 32.0f);        // dtw_loss
            out[NB * TT + 3] = sqrtf(s);                  // rmse_loss
        }
    }
}

extern "C" void kernel_launch(void* const* d_in, const int* in_sizes, int n_in,
                              void* d_out, int out_size, void* d_ws, size_t ws_size,
                              hipStream_t stream) {
    const float* pred_map = (const float*)d_in[0];
    const int*   lat_idx  = (const int*)d_in[1];
    const float* omega    = (const float*)d_in[2];
    const float* omni     = (const float*)d_in[3];
    float* out = (float*)d_out;
    float* ws  = (float*)d_ws;

    fused_kernel<<<NB, 64, 0, stream>>>(pred_map, lat_idx, omega, omni, out, ws);
}